// Round 7
// baseline (258.488 us; speedup 1.0000x reference)
//
#include <hip/hip_runtime.h>

#define S_DEPTH 128
#define N_RES   512
#define E_DIM   256
#define P_DIM   32
#define C_DIM   128

typedef short bh8 __attribute__((ext_vector_type(8)));   // 8 x bf16 (raw shorts)
typedef short sh4 __attribute__((ext_vector_type(4)));   // 4 x bf16
typedef float fx4 __attribute__((ext_vector_type(4)));   // MFMA f32 accumulator

__device__ __forceinline__ unsigned short f2bf(float x){
    unsigned int u = __builtin_bit_cast(unsigned int, x);
    u += 0x7fffu + ((u >> 16) & 1u);          // round-to-nearest-even
    return (unsigned short)(u >> 16);
}

// ---------------------------------------------------------------------------
// K0: transpose weights to bf16. 48 blocks x 256 = 12288 threads = 8192+4096.
// ---------------------------------------------------------------------------
__global__ void prep_kernel(const float* __restrict__ Wa, const float* __restrict__ Wb,
                            const float* __restrict__ Wp,
                            unsigned short* __restrict__ WaT, unsigned short* __restrict__ WbT,
                            unsigned short* __restrict__ WpT){
    int tid = blockIdx.x * 256 + threadIdx.x;
    if (tid < 8192){
        int p = tid >> 8, e = tid & 255;
        WaT[tid] = f2bf(Wa[e * P_DIM + p]);
        WbT[tid] = f2bf(Wb[e * P_DIM + p]);
    } else {
        int i = tid - 8192;
        int c = i >> 5, p = i & 31;
        WpT[i] = f2bf(Wp[p * C_DIM + c]);
    }
}

// ---------------------------------------------------------------------------
// KD: calibrated ~20 us delay probe. 1 block x 64 lanes, 12288 dependent FMAs
//     (~49k cycles @ ~4 cyc dep-latency). Runtime-seeded (no const-fold),
//     deterministic, stores to an unused d_ws corner (byte offset 16 MiB).
// ---------------------------------------------------------------------------
__global__ void delay_kernel(const float* __restrict__ seed, float* __restrict__ sink){
    float v = seed[0] * 1e-30f;
    #pragma unroll 1
    for (int i = 0; i < 12288; ++i)
        v = fmaf(v, 1.0000001f, 1.0e-9f);
    sink[threadIdx.x] = v;
}

// ---------------------------------------------------------------------------
// K1: LayerNorm + dual projection. (round-3 best, verbatim)
// ---------------------------------------------------------------------------
__global__ __launch_bounds__(256, 4) void lnproj_kernel(
    const float* __restrict__ x, const float* __restrict__ gamma, const float* __restrict__ beta,
    const unsigned short* __restrict__ WaT, const unsigned short* __restrict__ WbT,
    const float* __restrict__ ba, const float* __restrict__ bb,
    unsigned short* __restrict__ aT, unsigned short* __restrict__ bT)
{
    __shared__ __align__(16) char smem[64 * 512];      // 64 s-rows x 512 B = 32 KB
    const int n0   = blockIdx.x;
    const int sh   = blockIdx.y;                       // s-half (0/1)
    const int tid  = threadIdx.x;
    const int lane = tid & 63;
    const int w    = tid >> 6;                         // 4 waves
    const int l15  = lane & 15;
    const int lq   = lane >> 4;

    const float4 g4 = *(const float4*)(gamma + lane * 4);
    const float4 b4 = *(const float4*)(beta  + lane * 4);

    // ---- phase 1: LN, 16 rows per wave ----
    #pragma unroll 4
    for (int rr = 0; rr < 16; ++rr){
        int s_loc = w * 16 + rr;
        int s     = sh * 64 + s_loc;
        float4 v = *(const float4*)(x + ((size_t)(s * N_RES + n0)) * E_DIM + lane * 4);
        float sum = v.x + v.y + v.z + v.w;
        float sq  = v.x*v.x + v.y*v.y + v.z*v.z + v.w*v.w;
        #pragma unroll
        for (int m = 1; m < 64; m <<= 1){
            sum += __shfl_xor(sum, m);
            sq  += __shfl_xor(sq,  m);
        }
        float mu  = sum * (1.0f / E_DIM);
        float inv = rsqrtf(sq * (1.0f / E_DIM) - mu * mu + 1e-5f);
        ushort4 pk;
        pk.x = f2bf((v.x - mu) * inv * g4.x + b4.x);
        pk.y = f2bf((v.y - mu) * inv * g4.y + b4.y);
        pk.z = f2bf((v.z - mu) * inv * g4.z + b4.z);
        pk.w = f2bf((v.w - mu) * inv * g4.w + b4.w);
        int boff = s_loc * 512 + lane * 8;
        boff ^= (s_loc & 7) << 4;                      // 16-B-granule XOR swizzle
        *(ushort4*)(smem + boff) = pk;
    }
    __syncthreads();

    // ---- phase 2: wave w owns s-tile w (16 s-rows). D[s][p]. ----
    fx4 accA[2], accB[2];                              // [pt]
    #pragma unroll
    for (int pt = 0; pt < 2; ++pt){
        accA[pt] = fx4{0.f, 0.f, 0.f, 0.f};
        accB[pt] = fx4{0.f, 0.f, 0.f, 0.f};
    }
    const int srow = w * 16 + l15;

    #pragma unroll
    for (int ks = 0; ks < 8; ++ks){                    // K = 256 = 8 x 32
        int boff = srow * 512 + (ks * 32 + lq * 8) * 2;
        boff ^= (srow & 7) << 4;
        bh8 xf = *(const bh8*)(smem + boff);           // A: row s, 8 contig k
        #pragma unroll
        for (int pt = 0; pt < 2; ++pt){
            int off = (pt * 16 + l15) * E_DIM + ks * 32 + lq * 8;   // B: col p
            bh8 wa = *(const bh8*)(WaT + off);
            bh8 wb = *(const bh8*)(WbT + off);
            accA[pt] = __builtin_amdgcn_mfma_f32_16x16x32_bf16(xf, wa, accA[pt], 0, 0, 0);
            accB[pt] = __builtin_amdgcn_mfma_f32_16x16x32_bf16(xf, wb, accB[pt], 0, 0, 0);
        }
    }

    // ---- epilogue: D col = p (l15), row = s (lq*4+j) -> packed 8-B stores ----
    #pragma unroll
    for (int pt = 0; pt < 2; ++pt){
        int p = pt * 16 + l15;
        float bav = ba[p], bbv = bb[p];
        int s_base = sh * 64 + w * 16 + lq * 4;
        size_t o = ((size_t)p * N_RES + n0) * S_DEPTH + s_base;
        ushort4 ua, ub;
        ua.x = f2bf(accA[pt][0] + bav); ua.y = f2bf(accA[pt][1] + bav);
        ua.z = f2bf(accA[pt][2] + bav); ua.w = f2bf(accA[pt][3] + bav);
        ub.x = f2bf(accB[pt][0] + bbv); ub.y = f2bf(accB[pt][1] + bbv);
        ub.z = f2bf(accB[pt][2] + bbv); ub.w = f2bf(accB[pt][3] + bbv);
        *(ushort4*)(aT + o) = ua;
        *(ushort4*)(bT + o) = ub;
    }
}

// ---------------------------------------------------------------------------
// K2: fused batched outer (mean over S) + Wp projection + bias.
//   (round-3 best, verbatim: 256 blocks, 32x32 tile, 512 thr, 64 KB LDS,
//    b64 LDS transpose with 8-B-granule XOR swizzle, identity block order,
//    regular stores)
// ---------------------------------------------------------------------------
__global__ __launch_bounds__(512, 4) void outer_kernel(
    const unsigned short* __restrict__ aT, const unsigned short* __restrict__ bT,
    const unsigned short* __restrict__ WpT, const float* __restrict__ bp,
    float* __restrict__ out)
{
    __shared__ __align__(16) char smem[1024 * 64];     // [nm=1024][32 p x 2B], swizzled
    const int tn = blockIdx.x >> 4, tm = blockIdx.x & 15;
    const int n0 = tn * 32, m0 = tm * 32;
    const int tid  = threadIdx.x;
    const int lane = tid & 63;
    const int w    = tid >> 6;                         // 8 waves
    const int l15  = lane & 15;
    const int lq   = lane >> 4;

    // ---- stage 1: outer products, 4 p per wave, all accs live ----
    fx4 acc[4][2][2];                                  // [q][ti(n)][tj(m)]
    #pragma unroll
    for (int q = 0; q < 4; ++q)
        #pragma unroll
        for (int ti = 0; ti < 2; ++ti)
            #pragma unroll
            for (int tj = 0; tj < 2; ++tj)
                acc[q][ti][tj] = fx4{0.f, 0.f, 0.f, 0.f};

    #pragma unroll
    for (int ks = 0; ks < 4; ++ks){                    // K = S = 128 = 4 x 32
        #pragma unroll
        for (int q = 0; q < 4; ++q){
            int p = w * 4 + q;
            size_t kbase = (size_t)p * N_RES * S_DEPTH + ks * 32 + lq * 8;
            bh8 af[2], bfv[2];
            #pragma unroll
            for (int t = 0; t < 2; ++t){
                af[t]  = *(const bh8*)(aT + kbase + (size_t)(n0 + t * 16 + l15) * S_DEPTH);
                bfv[t] = *(const bh8*)(bT + kbase + (size_t)(m0 + t * 16 + l15) * S_DEPTH);
            }
            #pragma unroll
            for (int ti = 0; ti < 2; ++ti)
                #pragma unroll
                for (int tj = 0; tj < 2; ++tj)
                    acc[q][ti][tj] = __builtin_amdgcn_mfma_f32_16x16x32_bf16(
                                         af[ti], bfv[tj], acc[q][ti][tj], 0, 0, 0);
        }
    }

    // ---- stage 1b: pack 4 p per lane -> one b64 LDS write per (ti,tj,j) ----
    #pragma unroll
    for (int ti = 0; ti < 2; ++ti)
        #pragma unroll
        for (int tj = 0; tj < 2; ++tj)
            #pragma unroll
            for (int j = 0; j < 4; ++j){
                int nm  = (ti * 16 + lq * 4 + j) * 32 + (tj * 16 + l15);
                int swz = ((nm >> 1) & 3) ^ (((nm >> 7) & 3) << 1);
                sh4 v;
                #pragma unroll
                for (int q = 0; q < 4; ++q)
                    v[q] = (short)f2bf(acc[q][ti][tj][j] * (1.0f / S_DEPTH));
                *(sh4*)(smem + nm * 64 + ((w ^ swz) << 3)) = v;
            }
    __syncthreads();

    // ---- stage 2: project P -> C, fused bias, f32 stores ----
    bh8   wpf[8];
    float bpv[8];
    #pragma unroll
    for (int ct = 0; ct < 8; ++ct){
        wpf[ct] = *(const bh8*)(WpT + (ct * 16 + l15) * P_DIM + lq * 8);  // B: col c, k=p
        bpv[ct] = bp[ct * 16 + l15];
    }
    #pragma unroll
    for (int mi = 0; mi < 8; ++mi){
        int mt  = w * 8 + mi;                          // 64 row-tiles / 8 waves
        int nm  = mt * 16 + l15;
        int swz = ((nm >> 1) & 3) ^ (((nm >> 7) & 3) << 1);
        sh4 lo = *(const sh4*)(smem + nm * 64 + (((2 * lq)     ^ swz) << 3));
        sh4 hi = *(const sh4*)(smem + nm * 64 + (((2 * lq + 1) ^ swz) << 3));
        bh8 of = __builtin_shufflevector(lo, hi, 0, 1, 2, 3, 4, 5, 6, 7);  // A: row nm, k=p
        #pragma unroll
        for (int ct = 0; ct < 8; ++ct){
            fx4 d = __builtin_amdgcn_mfma_f32_16x16x32_bf16(
                        of, wpf[ct], fx4{0.f, 0.f, 0.f, 0.f}, 0, 0, 0);
            #pragma unroll
            for (int j = 0; j < 4; ++j){
                int nmr = mt * 16 + lq * 4 + j;        // D row -> nm index
                int n = nmr >> 5, m = nmr & 31;
                out[(((size_t)(n0 + n) * N_RES) + m0 + m) * C_DIM + ct * 16 + l15]
                    = d[j] + bpv[ct];
            }
        }
    }
}

// ---------------------------------------------------------------------------
extern "C" void kernel_launch(void* const* d_in, const int* in_sizes, int n_in,
                              void* d_out, int out_size, void* d_ws, size_t ws_size,
                              hipStream_t stream){
    const float* msa   = (const float*)d_in[0];
    const float* gamma = (const float*)d_in[1];
    const float* beta  = (const float*)d_in[2];
    const float* Wa    = (const float*)d_in[3];
    const float* ba    = (const float*)d_in[4];
    const float* Wb    = (const float*)d_in[5];
    const float* bb    = (const float*)d_in[6];
    const float* Wp    = (const float*)d_in[7];
    const float* bp    = (const float*)d_in[8];
    float* out = (float*)d_out;

    // workspace (ushort elems): aT | bT | WaT | WbT | WpT ; delay sink at +16 MiB
    unsigned short* ws  = (unsigned short*)d_ws;
    unsigned short* aT  = ws;                        // 32*512*128 = 2097152
    unsigned short* bT  = ws + 2097152;
    unsigned short* WaT = ws + 4194304;              // 8192
    unsigned short* WbT = WaT + 8192;                // 8192
    unsigned short* WpT = WbT + 8192;                // 4096
    float* sink = (float*)((char*)d_ws + (16u << 20));

    prep_kernel<<<48, 256, 0, stream>>>(Wa, Wb, Wp, WaT, WbT, WpT);
    lnproj_kernel<<<dim3(N_RES, 2), 256, 0, stream>>>(msa, gamma, beta, WaT, WbT, ba, bb, aT, bT);
    outer_kernel<<<256, 512, 0, stream>>>(aT, bT, WpT, bp, out);
    delay_kernel<<<1, 64, 0, stream>>>(bp, sink);    // ~20 us calibrated probe
}

// Round 8
// 99.837 us; speedup vs baseline: 2.5891x; 2.5891x over previous
//
#include <hip/hip_runtime.h>

#define S_DEPTH 128
#define N_RES   512
#define E_DIM   256
#define P_DIM   32
#define C_DIM   128

typedef short bh8 __attribute__((ext_vector_type(8)));   // 8 x bf16 (raw shorts)
typedef short sh4 __attribute__((ext_vector_type(4)));   // 4 x bf16
typedef float fx4 __attribute__((ext_vector_type(4)));   // MFMA f32 accumulator

__device__ __forceinline__ unsigned short f2bf(float x){
    unsigned int u = __builtin_bit_cast(unsigned int, x);
    u += 0x7fffu + ((u >> 16) & 1u);          // round-to-nearest-even
    return (unsigned short)(u >> 16);
}

// ---------------------------------------------------------------------------
// K0: transpose weights to bf16. 48 blocks x 256 = 12288 threads = 8192+4096.
// ---------------------------------------------------------------------------
__global__ void prep_kernel(const float* __restrict__ Wa, const float* __restrict__ Wb,
                            const float* __restrict__ Wp,
                            unsigned short* __restrict__ WaT, unsigned short* __restrict__ WbT,
                            unsigned short* __restrict__ WpT){
    int tid = blockIdx.x * 256 + threadIdx.x;
    if (tid < 8192){
        int p = tid >> 8, e = tid & 255;
        WaT[tid] = f2bf(Wa[e * P_DIM + p]);
        WbT[tid] = f2bf(Wb[e * P_DIM + p]);
    } else {
        int i = tid - 8192;
        int c = i >> 5, p = i & 31;
        WpT[i] = f2bf(Wp[p * C_DIM + c]);
    }
}

// ---------------------------------------------------------------------------
// K1: LayerNorm + dual projection. (round-3 best, verbatim)
//     PROBE: launched TWICE this round (idempotent) to measure t(K1) exactly.
// ---------------------------------------------------------------------------
__global__ __launch_bounds__(256, 4) void lnproj_kernel(
    const float* __restrict__ x, const float* __restrict__ gamma, const float* __restrict__ beta,
    const unsigned short* __restrict__ WaT, const unsigned short* __restrict__ WbT,
    const float* __restrict__ ba, const float* __restrict__ bb,
    unsigned short* __restrict__ aT, unsigned short* __restrict__ bT)
{
    __shared__ __align__(16) char smem[64 * 512];      // 64 s-rows x 512 B = 32 KB
    const int n0   = blockIdx.x;
    const int sh   = blockIdx.y;                       // s-half (0/1)
    const int tid  = threadIdx.x;
    const int lane = tid & 63;
    const int w    = tid >> 6;                         // 4 waves
    const int l15  = lane & 15;
    const int lq   = lane >> 4;

    const float4 g4 = *(const float4*)(gamma + lane * 4);
    const float4 b4 = *(const float4*)(beta  + lane * 4);

    // ---- phase 1: LN, 16 rows per wave ----
    #pragma unroll 4
    for (int rr = 0; rr < 16; ++rr){
        int s_loc = w * 16 + rr;
        int s     = sh * 64 + s_loc;
        float4 v = *(const float4*)(x + ((size_t)(s * N_RES + n0)) * E_DIM + lane * 4);
        float sum = v.x + v.y + v.z + v.w;
        float sq  = v.x*v.x + v.y*v.y + v.z*v.z + v.w*v.w;
        #pragma unroll
        for (int m = 1; m < 64; m <<= 1){
            sum += __shfl_xor(sum, m);
            sq  += __shfl_xor(sq,  m);
        }
        float mu  = sum * (1.0f / E_DIM);
        float inv = rsqrtf(sq * (1.0f / E_DIM) - mu * mu + 1e-5f);
        ushort4 pk;
        pk.x = f2bf((v.x - mu) * inv * g4.x + b4.x);
        pk.y = f2bf((v.y - mu) * inv * g4.y + b4.y);
        pk.z = f2bf((v.z - mu) * inv * g4.z + b4.z);
        pk.w = f2bf((v.w - mu) * inv * g4.w + b4.w);
        int boff = s_loc * 512 + lane * 8;
        boff ^= (s_loc & 7) << 4;                      // 16-B-granule XOR swizzle
        *(ushort4*)(smem + boff) = pk;
    }
    __syncthreads();

    // ---- phase 2: wave w owns s-tile w (16 s-rows). D[s][p]. ----
    fx4 accA[2], accB[2];                              // [pt]
    #pragma unroll
    for (int pt = 0; pt < 2; ++pt){
        accA[pt] = fx4{0.f, 0.f, 0.f, 0.f};
        accB[pt] = fx4{0.f, 0.f, 0.f, 0.f};
    }
    const int srow = w * 16 + l15;

    #pragma unroll
    for (int ks = 0; ks < 8; ++ks){                    // K = 256 = 8 x 32
        int boff = srow * 512 + (ks * 32 + lq * 8) * 2;
        boff ^= (srow & 7) << 4;
        bh8 xf = *(const bh8*)(smem + boff);           // A: row s, 8 contig k
        #pragma unroll
        for (int pt = 0; pt < 2; ++pt){
            int off = (pt * 16 + l15) * E_DIM + ks * 32 + lq * 8;   // B: col p
            bh8 wa = *(const bh8*)(WaT + off);
            bh8 wb = *(const bh8*)(WbT + off);
            accA[pt] = __builtin_amdgcn_mfma_f32_16x16x32_bf16(xf, wa, accA[pt], 0, 0, 0);
            accB[pt] = __builtin_amdgcn_mfma_f32_16x16x32_bf16(xf, wb, accB[pt], 0, 0, 0);
        }
    }

    // ---- epilogue: D col = p (l15), row = s (lq*4+j) -> packed 8-B stores ----
    #pragma unroll
    for (int pt = 0; pt < 2; ++pt){
        int p = pt * 16 + l15;
        float bav = ba[p], bbv = bb[p];
        int s_base = sh * 64 + w * 16 + lq * 4;
        size_t o = ((size_t)p * N_RES + n0) * S_DEPTH + s_base;
        ushort4 ua, ub;
        ua.x = f2bf(accA[pt][0] + bav); ua.y = f2bf(accA[pt][1] + bav);
        ua.z = f2bf(accA[pt][2] + bav); ua.w = f2bf(accA[pt][3] + bav);
        ub.x = f2bf(accB[pt][0] + bbv); ub.y = f2bf(accB[pt][1] + bbv);
        ub.z = f2bf(accB[pt][2] + bbv); ub.w = f2bf(accB[pt][3] + bbv);
        *(ushort4*)(aT + o) = ua;
        *(ushort4*)(bT + o) = ub;
    }
}

// ---------------------------------------------------------------------------
// K2: fused batched outer (mean over S) + Wp projection + bias.
//   (round-3 best, verbatim)
// ---------------------------------------------------------------------------
__global__ __launch_bounds__(512, 4) void outer_kernel(
    const unsigned short* __restrict__ aT, const unsigned short* __restrict__ bT,
    const unsigned short* __restrict__ WpT, const float* __restrict__ bp,
    float* __restrict__ out)
{
    __shared__ __align__(16) char smem[1024 * 64];     // [nm=1024][32 p x 2B], swizzled
    const int tn = blockIdx.x >> 4, tm = blockIdx.x & 15;
    const int n0 = tn * 32, m0 = tm * 32;
    const int tid  = threadIdx.x;
    const int lane = tid & 63;
    const int w    = tid >> 6;                         // 8 waves
    const int l15  = lane & 15;
    const int lq   = lane >> 4;

    // ---- stage 1: outer products, 4 p per wave, all accs live ----
    fx4 acc[4][2][2];                                  // [q][ti(n)][tj(m)]
    #pragma unroll
    for (int q = 0; q < 4; ++q)
        #pragma unroll
        for (int ti = 0; ti < 2; ++ti)
            #pragma unroll
            for (int tj = 0; tj < 2; ++tj)
                acc[q][ti][tj] = fx4{0.f, 0.f, 0.f, 0.f};

    #pragma unroll
    for (int ks = 0; ks < 4; ++ks){                    // K = S = 128 = 4 x 32
        #pragma unroll
        for (int q = 0; q < 4; ++q){
            int p = w * 4 + q;
            size_t kbase = (size_t)p * N_RES * S_DEPTH + ks * 32 + lq * 8;
            bh8 af[2], bfv[2];
            #pragma unroll
            for (int t = 0; t < 2; ++t){
                af[t]  = *(const bh8*)(aT + kbase + (size_t)(n0 + t * 16 + l15) * S_DEPTH);
                bfv[t] = *(const bh8*)(bT + kbase + (size_t)(m0 + t * 16 + l15) * S_DEPTH);
            }
            #pragma unroll
            for (int ti = 0; ti < 2; ++ti)
                #pragma unroll
                for (int tj = 0; tj < 2; ++tj)
                    acc[q][ti][tj] = __builtin_amdgcn_mfma_f32_16x16x32_bf16(
                                         af[ti], bfv[tj], acc[q][ti][tj], 0, 0, 0);
        }
    }

    // ---- stage 1b: pack 4 p per lane -> one b64 LDS write per (ti,tj,j) ----
    #pragma unroll
    for (int ti = 0; ti < 2; ++ti)
        #pragma unroll
        for (int tj = 0; tj < 2; ++tj)
            #pragma unroll
            for (int j = 0; j < 4; ++j){
                int nm  = (ti * 16 + lq * 4 + j) * 32 + (tj * 16 + l15);
                int swz = ((nm >> 1) & 3) ^ (((nm >> 7) & 3) << 1);
                sh4 v;
                #pragma unroll
                for (int q = 0; q < 4; ++q)
                    v[q] = (short)f2bf(acc[q][ti][tj][j] * (1.0f / S_DEPTH));
                *(sh4*)(smem + nm * 64 + ((w ^ swz) << 3)) = v;
            }
    __syncthreads();

    // ---- stage 2: project P -> C, fused bias, f32 stores ----
    bh8   wpf[8];
    float bpv[8];
    #pragma unroll
    for (int ct = 0; ct < 8; ++ct){
        wpf[ct] = *(const bh8*)(WpT + (ct * 16 + l15) * P_DIM + lq * 8);  // B: col c, k=p
        bpv[ct] = bp[ct * 16 + l15];
    }
    #pragma unroll
    for (int mi = 0; mi < 8; ++mi){
        int mt  = w * 8 + mi;                          // 64 row-tiles / 8 waves
        int nm  = mt * 16 + l15;
        int swz = ((nm >> 1) & 3) ^ (((nm >> 7) & 3) << 1);
        sh4 lo = *(const sh4*)(smem + nm * 64 + (((2 * lq)     ^ swz) << 3));
        sh4 hi = *(const sh4*)(smem + nm * 64 + (((2 * lq + 1) ^ swz) << 3));
        bh8 of = __builtin_shufflevector(lo, hi, 0, 1, 2, 3, 4, 5, 6, 7);  // A: row nm, k=p
        #pragma unroll
        for (int ct = 0; ct < 8; ++ct){
            fx4 d = __builtin_amdgcn_mfma_f32_16x16x32_bf16(
                        of, wpf[ct], fx4{0.f, 0.f, 0.f, 0.f}, 0, 0, 0);
            #pragma unroll
            for (int j = 0; j < 4; ++j){
                int nmr = mt * 16 + lq * 4 + j;        // D row -> nm index
                int n = nmr >> 5, m = nmr & 31;
                out[(((size_t)(n0 + n) * N_RES) + m0 + m) * C_DIM + ct * 16 + l15]
                    = d[j] + bpv[ct];
            }
        }
    }
}

// ---------------------------------------------------------------------------
extern "C" void kernel_launch(void* const* d_in, const int* in_sizes, int n_in,
                              void* d_out, int out_size, void* d_ws, size_t ws_size,
                              hipStream_t stream){
    const float* msa   = (const float*)d_in[0];
    const float* gamma = (const float*)d_in[1];
    const float* beta  = (const float*)d_in[2];
    const float* Wa    = (const float*)d_in[3];
    const float* ba    = (const float*)d_in[4];
    const float* Wb    = (const float*)d_in[5];
    const float* bb    = (const float*)d_in[6];
    const float* Wp    = (const float*)d_in[7];
    const float* bp    = (const float*)d_in[8];
    float* out = (float*)d_out;

    // workspace (ushort elems): aT | bT | WaT | WbT | WpT
    unsigned short* ws  = (unsigned short*)d_ws;
    unsigned short* aT  = ws;                        // 32*512*128 = 2097152
    unsigned short* bT  = ws + 2097152;
    unsigned short* WaT = ws + 4194304;              // 8192
    unsigned short* WbT = WaT + 8192;                // 8192
    unsigned short* WpT = WbT + 8192;                // 4096

    prep_kernel<<<48, 256, 0, stream>>>(Wa, Wb, Wp, WaT, WbT, WpT);
    // PROBE: K1 launched twice (idempotent). t(K1) = dur - 76.7us (r3 baseline).
    lnproj_kernel<<<dim3(N_RES, 2), 256, 0, stream>>>(msa, gamma, beta, WaT, WbT, ba, bb, aT, bT);
    lnproj_kernel<<<dim3(N_RES, 2), 256, 0, stream>>>(msa, gamma, beta, WaT, WbT, ba, bb, aT, bT);
    outer_kernel<<<256, 512, 0, stream>>>(aT, bT, WpT, bp, out);
}

// Round 10
// 84.697 us; speedup vs baseline: 3.0519x; 1.1788x over previous
//
#include <hip/hip_runtime.h>

#define S_DEPTH 128
#define N_RES   512
#define E_DIM   256
#define P_DIM   32
#define C_DIM   128

typedef short bh8 __attribute__((ext_vector_type(8)));   // 8 x bf16 (raw shorts)
typedef short sh4 __attribute__((ext_vector_type(4)));   // 4 x bf16
typedef float fx4 __attribute__((ext_vector_type(4)));   // MFMA f32 accumulator

__device__ __forceinline__ unsigned short f2bf(float x){
    unsigned int u = __builtin_bit_cast(unsigned int, x);
    u += 0x7fffu + ((u >> 16) & 1u);          // round-to-nearest-even
    return (unsigned short)(u >> 16);
}

// ---------------------------------------------------------------------------
// K0: build fused-LN weights.
//   W2T[80][256] bf16: rows 0-31 = (gamma*Wa)^T, 32-63 = (gamma*Wb)^T,
//                      row 64 = ones (row-sum column), 65-79 = zero pad.
//   WpT[128][32] bf16 (c-major).  SB[128] f32: [0..63] S = sum_e gamma*W,
//   [64..127] B = beta@W + bias.   97 blocks x 256 thr.
// ---------------------------------------------------------------------------
__global__ void prep_kernel(const float* __restrict__ Wa, const float* __restrict__ Wb,
                            const float* __restrict__ Wp,
                            const float* __restrict__ gamma, const float* __restrict__ beta,
                            const float* __restrict__ ba, const float* __restrict__ bb,
                            unsigned short* __restrict__ W2T, unsigned short* __restrict__ WpT,
                            float* __restrict__ SB){
    int tid = blockIdx.x * 256 + threadIdx.x;
    if (tid < 20480){                              // 80 rows x 256 e
        int r = tid >> 8, e = tid & 255;
        float v;
        if      (r < 32) v = gamma[e] * Wa[e * P_DIM + r];
        else if (r < 64) v = gamma[e] * Wb[e * P_DIM + (r - 32)];
        else if (r == 64) v = 1.0f;
        else              v = 0.0f;
        W2T[tid] = f2bf(v);
    } else if (tid < 24576){                       // WpT: 4096 = C*P
        int i = tid - 20480;
        int c = i >> 5, p = i & 31;
        WpT[i] = f2bf(Wp[p * C_DIM + c]);
    } else if (tid < 24704){                       // S and B: 128 threads
        int i   = tid - 24576;                     // [k(2)][mat(2)][p(32)]
        int k   = i >> 6;                          // 0 = S, 1 = B
        int mat = (i >> 5) & 1;
        int p   = i & 31;
        const float* W = mat ? Wb : Wa;
        const float* g = k ? beta : gamma;
        float s = 0.f;
        #pragma unroll 4
        for (int e = 0; e < E_DIM; ++e)
            s = fmaf(g[e], W[e * P_DIM + p], s);
        if (k) s += (mat ? bb : ba)[p];
        SB[i] = s;
    }
}

// ---------------------------------------------------------------------------
// K1: fused LayerNorm + dual projection, LN stats on the MFMA pipe.
//   Grid (512 n, 2 s-halves), 256 thr, 32 KB + 512 B LDS.
//   Phase 0: f32 load -> bf16 -> swizzled LDS (no reduction).
//   Phase 1: Y[s][0..79] = x @ W2 (col 64 = row sums); SS = x @ x^T
//            (diag = sum x^2). 48 MFMA / wave.
//   Stats exchange via LDS with predicates read straight off the D-layout
//   rule (col=lane&15, row=(lane>>4)*4+reg): l15==0 lanes hold rowsums,
//   l15==lq*4+j lanes hold diag(l15) in ss[j]. Variance clamped >= 0.
//   Epilogue: a = inv*(Y - mu*S) + B, packed 8-B stores.
// ---------------------------------------------------------------------------
__global__ __launch_bounds__(256, 4) void lnproj_kernel(
    const float* __restrict__ x, const unsigned short* __restrict__ W2T,
    const float* __restrict__ SB,
    unsigned short* __restrict__ aT, unsigned short* __restrict__ bT)
{
    __shared__ __align__(16) char smem[64 * 512];      // 64 s-rows x 512 B bf16
    __shared__ float stats[2][4][16];                  // [kind][wave][row]
    const int n0   = blockIdx.x;
    const int sh   = blockIdx.y;                       // s-half (0/1)
    const int tid  = threadIdx.x;
    const int lane = tid & 63;
    const int w    = tid >> 6;                         // 4 waves
    const int l15  = lane & 15;
    const int lq   = lane >> 4;

    // ---- phase 0: convert 16 rows/wave to bf16 LDS ----
    #pragma unroll 4
    for (int rr = 0; rr < 16; ++rr){
        int s_loc = w * 16 + rr;
        int s     = sh * 64 + s_loc;
        float4 v = *(const float4*)(x + ((size_t)(s * N_RES + n0)) * E_DIM + lane * 4);
        ushort4 pk = { f2bf(v.x), f2bf(v.y), f2bf(v.z), f2bf(v.w) };
        int boff = s_loc * 512 + lane * 8;
        boff ^= (s_loc & 7) << 4;                      // 16-B-granule XOR swizzle
        *(ushort4*)(smem + boff) = pk;
    }
    __syncthreads();

    // ---- phase 1: MFMA. wave w owns s-rows [w*16, w*16+16). ----
    fx4 y[5], ss;
    #pragma unroll
    for (int t = 0; t < 5; ++t) y[t] = fx4{0.f, 0.f, 0.f, 0.f};
    ss = fx4{0.f, 0.f, 0.f, 0.f};
    const int srow = w * 16 + l15;

    #pragma unroll
    for (int ks = 0; ks < 8; ++ks){                    // K = 256 = 8 x 32
        int boff = srow * 512 + (ks * 32 + lq * 8) * 2;
        boff ^= (srow & 7) << 4;
        bh8 xf = *(const bh8*)(smem + boff);           // A: row s, 8 contig k
        ss = __builtin_amdgcn_mfma_f32_16x16x32_bf16(xf, xf, ss, 0, 0, 0);
        #pragma unroll
        for (int t = 0; t < 5; ++t){
            bh8 wf = *(const bh8*)(W2T + (t * 16 + l15) * E_DIM + ks * 32 + lq * 8);
            y[t] = __builtin_amdgcn_mfma_f32_16x16x32_bf16(xf, wf, y[t], 0, 0, 0);
        }
    }

    // ---- stats exchange (LDS, predicate from D-layout rule) ----
    if (l15 == 0){                                     // col 0 = ones column
        #pragma unroll
        for (int j = 0; j < 4; ++j)
            stats[0][w][lq * 4 + j] = y[4][j];         // rowsum of row lq*4+j
    }
    #pragma unroll
    for (int j = 0; j < 4; ++j)
        if (l15 == lq * 4 + j)                         // diag: row==col==l15
            stats[1][w][l15] = ss[j];
    __syncthreads();

    float mu[4], inv[4];
    #pragma unroll
    for (int j = 0; j < 4; ++j){
        float msum = stats[0][w][lq * 4 + j];
        float ssq  = stats[1][w][lq * 4 + j];
        float m = msum * (1.0f / E_DIM);
        mu[j]  = m;
        inv[j] = rsqrtf(fmaxf(ssq * (1.0f / E_DIM) - m * m, 0.0f) + 1e-5f);
    }

    // ---- epilogue: tile t -> mat = t>>1, p = (t&1)*16+l15 ----
    const int s_base = sh * 64 + w * 16 + lq * 4;
    #pragma unroll
    for (int t = 0; t < 4; ++t){
        float S  = SB[t * 16 + l15];
        float Bf = SB[64 + t * 16 + l15];
        ushort4 u;
        u.x = f2bf(fmaf(inv[0], y[t][0] - mu[0] * S, Bf));
        u.y = f2bf(fmaf(inv[1], y[t][1] - mu[1] * S, Bf));
        u.z = f2bf(fmaf(inv[2], y[t][2] - mu[2] * S, Bf));
        u.w = f2bf(fmaf(inv[3], y[t][3] - mu[3] * S, Bf));
        int p = (t & 1) * 16 + l15;
        unsigned short* dst = (t >> 1) ? bT : aT;
        *(ushort4*)(dst + ((size_t)p * N_RES + n0) * S_DEPTH + s_base) = u;
    }
}

// ---------------------------------------------------------------------------
// K2: fused batched outer (mean over S) + Wp projection + bias.
//   r3 geometry verbatim (256 blocks, 32x32 tile, 512 thr, 64 KB LDS, b64
//   swizzled LDS transpose). ONE delta vs r3: stage-2 MFMA operands swapped
//   (A = WpT-frag, B = outer-frag) so D[c][nm] gives each lane 4 consecutive
//   c -> float4 stores (64 x 16 B per lane vs 256 x 4 B).
// ---------------------------------------------------------------------------
__global__ __launch_bounds__(512, 4) void outer_kernel(
    const unsigned short* __restrict__ aT, const unsigned short* __restrict__ bT,
    const unsigned short* __restrict__ WpT, const float* __restrict__ bp,
    float* __restrict__ out)
{
    __shared__ __align__(16) char smem[1024 * 64];     // [nm=1024][32 p x 2B], swizzled
    const int tn = blockIdx.x >> 4, tm = blockIdx.x & 15;
    const int n0 = tn * 32, m0 = tm * 32;
    const int tid  = threadIdx.x;
    const int lane = tid & 63;
    const int w    = tid >> 6;                         // 8 waves
    const int l15  = lane & 15;
    const int lq   = lane >> 4;

    // ---- stage 1: outer products, 4 p per wave, all accs live ----
    fx4 acc[4][2][2];                                  // [q][ti(n)][tj(m)]
    #pragma unroll
    for (int q = 0; q < 4; ++q)
        #pragma unroll
        for (int ti = 0; ti < 2; ++ti)
            #pragma unroll
            for (int tj = 0; tj < 2; ++tj)
                acc[q][ti][tj] = fx4{0.f, 0.f, 0.f, 0.f};

    #pragma unroll
    for (int ks = 0; ks < 4; ++ks){                    // K = S = 128 = 4 x 32
        #pragma unroll
        for (int q = 0; q < 4; ++q){
            int p = w * 4 + q;
            size_t kbase = (size_t)p * N_RES * S_DEPTH + ks * 32 + lq * 8;
            bh8 af[2], bfv[2];
            #pragma unroll
            for (int t = 0; t < 2; ++t){
                af[t]  = *(const bh8*)(aT + kbase + (size_t)(n0 + t * 16 + l15) * S_DEPTH);
                bfv[t] = *(const bh8*)(bT + kbase + (size_t)(m0 + t * 16 + l15) * S_DEPTH);
            }
            #pragma unroll
            for (int ti = 0; ti < 2; ++ti)
                #pragma unroll
                for (int tj = 0; tj < 2; ++tj)
                    acc[q][ti][tj] = __builtin_amdgcn_mfma_f32_16x16x32_bf16(
                                         af[ti], bfv[tj], acc[q][ti][tj], 0, 0, 0);
        }
    }

    // ---- stage 1b: pack 4 p per lane -> one b64 LDS write per (ti,tj,j) ----
    #pragma unroll
    for (int ti = 0; ti < 2; ++ti)
        #pragma unroll
        for (int tj = 0; tj < 2; ++tj)
            #pragma unroll
            for (int j = 0; j < 4; ++j){
                int nm  = (ti * 16 + lq * 4 + j) * 32 + (tj * 16 + l15);
                int swz = ((nm >> 1) & 3) ^ (((nm >> 7) & 3) << 1);
                sh4 v;
                #pragma unroll
                for (int q = 0; q < 4; ++q)
                    v[q] = (short)f2bf(acc[q][ti][tj][j] * (1.0f / S_DEPTH));
                *(sh4*)(smem + nm * 64 + ((w ^ swz) << 3)) = v;
            }
    __syncthreads();

    // ---- stage 2: D[c][nm] = WpT-frag x outer-frag; float4 stores ----
    bh8    wpf[8];
    float4 bp4[8];
    #pragma unroll
    for (int ct = 0; ct < 8; ++ct){
        wpf[ct] = *(const bh8*)(WpT + (ct * 16 + l15) * P_DIM + lq * 8);  // A: row c, k=p
        bp4[ct] = *(const float4*)(bp + ct * 16 + lq * 4);
    }
    #pragma unroll
    for (int mi = 0; mi < 8; ++mi){
        int mt  = w * 8 + mi;                          // 64 nm-groups / 8 waves
        int nm  = mt * 16 + l15;
        int swz = ((nm >> 1) & 3) ^ (((nm >> 7) & 3) << 1);
        sh4 lo = *(const sh4*)(smem + nm * 64 + (((2 * lq)     ^ swz) << 3));
        sh4 hi = *(const sh4*)(smem + nm * 64 + (((2 * lq + 1) ^ swz) << 3));
        bh8 of = __builtin_shufflevector(lo, hi, 0, 1, 2, 3, 4, 5, 6, 7);  // B: col nm, k=p
        float* po = out + (((size_t)(n0 + (nm >> 5)) * N_RES) + m0 + (nm & 31)) * C_DIM;
        #pragma unroll
        for (int ct = 0; ct < 8; ++ct){
            fx4 d = __builtin_amdgcn_mfma_f32_16x16x32_bf16(
                        wpf[ct], of, fx4{0.f, 0.f, 0.f, 0.f}, 0, 0, 0);
            float4 o4 = { d[0] + bp4[ct].x, d[1] + bp4[ct].y,
                          d[2] + bp4[ct].z, d[3] + bp4[ct].w };
            *(float4*)(po + ct * 16 + lq * 4) = o4;    // c = ct*16 + lq*4 .. +4
        }
    }
}

// ---------------------------------------------------------------------------
extern "C" void kernel_launch(void* const* d_in, const int* in_sizes, int n_in,
                              void* d_out, int out_size, void* d_ws, size_t ws_size,
                              hipStream_t stream){
    const float* msa   = (const float*)d_in[0];
    const float* gamma = (const float*)d_in[1];
    const float* beta  = (const float*)d_in[2];
    const float* Wa    = (const float*)d_in[3];
    const float* ba    = (const float*)d_in[4];
    const float* Wb    = (const float*)d_in[5];
    const float* bb    = (const float*)d_in[6];
    const float* Wp    = (const float*)d_in[7];
    const float* bp    = (const float*)d_in[8];
    float* out = (float*)d_out;

    // workspace (ushort elems): aT | bT | W2T(20480) | WpT(4096) | SB(128 f32)
    unsigned short* ws  = (unsigned short*)d_ws;
    unsigned short* aT  = ws;                        // 32*512*128 = 2097152
    unsigned short* bT  = ws + 2097152;
    unsigned short* W2T = ws + 4194304;              // 80*256
    unsigned short* WpT = W2T + 20480;               // 4096
    float*          SB  = (float*)(ws + 4218880);    // 128 f32

    prep_kernel<<<97, 256, 0, stream>>>(Wa, Wb, Wp, gamma, beta, ba, bb, W2T, WpT, SB);
    lnproj_kernel<<<dim3(N_RES, 2), 256, 0, stream>>>(msa, W2T, SB, aT, bT);
    outer_kernel<<<256, 512, 0, stream>>>(aT, bT, WpT, bp, out);
}

// Round 11
// 77.892 us; speedup vs baseline: 3.3186x; 1.0874x over previous
//
#include <hip/hip_runtime.h>

#define S_DEPTH 128
#define N_RES   512
#define E_DIM   256
#define P_DIM   32
#define C_DIM   128

typedef short bh8 __attribute__((ext_vector_type(8)));   // 8 x bf16 (raw shorts)
typedef short sh4 __attribute__((ext_vector_type(4)));   // 4 x bf16
typedef float fx4 __attribute__((ext_vector_type(4)));   // MFMA f32 accumulator

__device__ __forceinline__ unsigned short f2bf(float x){
    unsigned int u = __builtin_bit_cast(unsigned int, x);
    u += 0x7fffu + ((u >> 16) & 1u);          // round-to-nearest-even
    return (unsigned short)(u >> 16);
}

// ---------------------------------------------------------------------------
// K0: build fused-LN weights. (r10, with SB reduction de-serialized: 4
//     independent chains instead of one 256-deep dependent fmaf chain)
// ---------------------------------------------------------------------------
__global__ void prep_kernel(const float* __restrict__ Wa, const float* __restrict__ Wb,
                            const float* __restrict__ Wp,
                            const float* __restrict__ gamma, const float* __restrict__ beta,
                            const float* __restrict__ ba, const float* __restrict__ bb,
                            unsigned short* __restrict__ W2T, unsigned short* __restrict__ WpT,
                            float* __restrict__ SB){
    int tid = blockIdx.x * 256 + threadIdx.x;
    if (tid < 20480){                              // 80 rows x 256 e
        int r = tid >> 8, e = tid & 255;
        float v;
        if      (r < 32) v = gamma[e] * Wa[e * P_DIM + r];
        else if (r < 64) v = gamma[e] * Wb[e * P_DIM + (r - 32)];
        else if (r == 64) v = 1.0f;
        else              v = 0.0f;
        W2T[tid] = f2bf(v);
    } else if (tid < 24576){                       // WpT: 4096 = C*P
        int i = tid - 20480;
        int c = i >> 5, p = i & 31;
        WpT[i] = f2bf(Wp[p * C_DIM + c]);
    } else if (tid < 24704){                       // S and B: 128 threads
        int i   = tid - 24576;                     // [k(2)][mat(2)][p(32)]
        int k   = i >> 6;                          // 0 = S, 1 = B
        int mat = (i >> 5) & 1;
        int p   = i & 31;
        const float* W = mat ? Wb : Wa;
        const float* g = k ? beta : gamma;
        float s0 = 0.f, s1 = 0.f, s2 = 0.f, s3 = 0.f;   // 4 independent chains
        #pragma unroll 4
        for (int e = 0; e < E_DIM; e += 4){
            s0 = fmaf(g[e  ], W[(e  ) * P_DIM + p], s0);
            s1 = fmaf(g[e+1], W[(e+1) * P_DIM + p], s1);
            s2 = fmaf(g[e+2], W[(e+2) * P_DIM + p], s2);
            s3 = fmaf(g[e+3], W[(e+3) * P_DIM + p], s3);
        }
        float s = (s0 + s1) + (s2 + s3);
        if (k) s += (mat ? bb : ba)[p];
        SB[i] = s;
    }
}

// ---------------------------------------------------------------------------
// K1: fused LayerNorm + dual projection, LN stats on the MFMA pipe.
//     (r10 verbatim — correctness verified, absmax 9.77e-4)
// ---------------------------------------------------------------------------
__global__ __launch_bounds__(256, 4) void lnproj_kernel(
    const float* __restrict__ x, const unsigned short* __restrict__ W2T,
    const float* __restrict__ SB,
    unsigned short* __restrict__ aT, unsigned short* __restrict__ bT)
{
    __shared__ __align__(16) char smem[64 * 512];      // 64 s-rows x 512 B bf16
    __shared__ float stats[2][4][16];                  // [kind][wave][row]
    const int n0   = blockIdx.x;
    const int sh   = blockIdx.y;                       // s-half (0/1)
    const int tid  = threadIdx.x;
    const int lane = tid & 63;
    const int w    = tid >> 6;                         // 4 waves
    const int l15  = lane & 15;
    const int lq   = lane >> 4;

    // ---- phase 0: convert 16 rows/wave to bf16 LDS ----
    #pragma unroll 4
    for (int rr = 0; rr < 16; ++rr){
        int s_loc = w * 16 + rr;
        int s     = sh * 64 + s_loc;
        float4 v = *(const float4*)(x + ((size_t)(s * N_RES + n0)) * E_DIM + lane * 4);
        ushort4 pk = { f2bf(v.x), f2bf(v.y), f2bf(v.z), f2bf(v.w) };
        int boff = s_loc * 512 + lane * 8;
        boff ^= (s_loc & 7) << 4;                      // 16-B-granule XOR swizzle
        *(ushort4*)(smem + boff) = pk;
    }
    __syncthreads();

    // ---- phase 1: MFMA. wave w owns s-rows [w*16, w*16+16). ----
    fx4 y[5], ss;
    #pragma unroll
    for (int t = 0; t < 5; ++t) y[t] = fx4{0.f, 0.f, 0.f, 0.f};
    ss = fx4{0.f, 0.f, 0.f, 0.f};
    const int srow = w * 16 + l15;

    #pragma unroll
    for (int ks = 0; ks < 8; ++ks){                    // K = 256 = 8 x 32
        int boff = srow * 512 + (ks * 32 + lq * 8) * 2;
        boff ^= (srow & 7) << 4;
        bh8 xf = *(const bh8*)(smem + boff);           // A: row s, 8 contig k
        ss = __builtin_amdgcn_mfma_f32_16x16x32_bf16(xf, xf, ss, 0, 0, 0);
        #pragma unroll
        for (int t = 0; t < 5; ++t){
            bh8 wf = *(const bh8*)(W2T + (t * 16 + l15) * E_DIM + ks * 32 + lq * 8);
            y[t] = __builtin_amdgcn_mfma_f32_16x16x32_bf16(xf, wf, y[t], 0, 0, 0);
        }
    }

    // ---- stats exchange (LDS, predicate from D-layout rule) ----
    if (l15 == 0){                                     // col 0 = ones column
        #pragma unroll
        for (int j = 0; j < 4; ++j)
            stats[0][w][lq * 4 + j] = y[4][j];         // rowsum of row lq*4+j
    }
    #pragma unroll
    for (int j = 0; j < 4; ++j)
        if (l15 == lq * 4 + j)                         // diag: row==col==l15
            stats[1][w][l15] = ss[j];
    __syncthreads();

    float mu[4], inv[4];
    #pragma unroll
    for (int j = 0; j < 4; ++j){
        float msum = stats[0][w][lq * 4 + j];
        float ssq  = stats[1][w][lq * 4 + j];
        float m = msum * (1.0f / E_DIM);
        mu[j]  = m;
        inv[j] = rsqrtf(fmaxf(ssq * (1.0f / E_DIM) - m * m, 0.0f) + 1e-5f);
    }

    // ---- epilogue: tile t -> mat = t>>1, p = (t&1)*16+l15 ----
    const int s_base = sh * 64 + w * 16 + lq * 4;
    #pragma unroll
    for (int t = 0; t < 4; ++t){
        float S  = SB[t * 16 + l15];
        float Bf = SB[64 + t * 16 + l15];
        ushort4 u;
        u.x = f2bf(fmaf(inv[0], y[t][0] - mu[0] * S, Bf));
        u.y = f2bf(fmaf(inv[1], y[t][1] - mu[1] * S, Bf));
        u.z = f2bf(fmaf(inv[2], y[t][2] - mu[2] * S, Bf));
        u.w = f2bf(fmaf(inv[3], y[t][3] - mu[3] * S, Bf));
        int p = (t & 1) * 16 + l15;
        unsigned short* dst = (t >> 1) ? bT : aT;
        *(ushort4*)(dst + ((size_t)p * N_RES + n0) * S_DEPTH + s_base) = u;
    }
}

// ---------------------------------------------------------------------------
// K2: fused batched outer (mean over S) + Wp projection + bias.
//   (round-3 best, VERBATIM — operand swap reverted for bisect)
// ---------------------------------------------------------------------------
__global__ __launch_bounds__(512, 4) void outer_kernel(
    const unsigned short* __restrict__ aT, const unsigned short* __restrict__ bT,
    const unsigned short* __restrict__ WpT, const float* __restrict__ bp,
    float* __restrict__ out)
{
    __shared__ __align__(16) char smem[1024 * 64];     // [nm=1024][32 p x 2B], swizzled
    const int tn = blockIdx.x >> 4, tm = blockIdx.x & 15;
    const int n0 = tn * 32, m0 = tm * 32;
    const int tid  = threadIdx.x;
    const int lane = tid & 63;
    const int w    = tid >> 6;                         // 8 waves
    const int l15  = lane & 15;
    const int lq   = lane >> 4;

    // ---- stage 1: outer products, 4 p per wave, all accs live ----
    fx4 acc[4][2][2];                                  // [q][ti(n)][tj(m)]
    #pragma unroll
    for (int q = 0; q < 4; ++q)
        #pragma unroll
        for (int ti = 0; ti < 2; ++ti)
            #pragma unroll
            for (int tj = 0; tj < 2; ++tj)
                acc[q][ti][tj] = fx4{0.f, 0.f, 0.f, 0.f};

    #pragma unroll
    for (int ks = 0; ks < 4; ++ks){                    // K = S = 128 = 4 x 32
        #pragma unroll
        for (int q = 0; q < 4; ++q){
            int p = w * 4 + q;
            size_t kbase = (size_t)p * N_RES * S_DEPTH + ks * 32 + lq * 8;
            bh8 af[2], bfv[2];
            #pragma unroll
            for (int t = 0; t < 2; ++t){
                af[t]  = *(const bh8*)(aT + kbase + (size_t)(n0 + t * 16 + l15) * S_DEPTH);
                bfv[t] = *(const bh8*)(bT + kbase + (size_t)(m0 + t * 16 + l15) * S_DEPTH);
            }
            #pragma unroll
            for (int ti = 0; ti < 2; ++ti)
                #pragma unroll
                for (int tj = 0; tj < 2; ++tj)
                    acc[q][ti][tj] = __builtin_amdgcn_mfma_f32_16x16x32_bf16(
                                         af[ti], bfv[tj], acc[q][ti][tj], 0, 0, 0);
        }
    }

    // ---- stage 1b: pack 4 p per lane -> one b64 LDS write per (ti,tj,j) ----
    #pragma unroll
    for (int ti = 0; ti < 2; ++ti)
        #pragma unroll
        for (int tj = 0; tj < 2; ++tj)
            #pragma unroll
            for (int j = 0; j < 4; ++j){
                int nm  = (ti * 16 + lq * 4 + j) * 32 + (tj * 16 + l15);
                int swz = ((nm >> 1) & 3) ^ (((nm >> 7) & 3) << 1);
                sh4 v;
                #pragma unroll
                for (int q = 0; q < 4; ++q)
                    v[q] = (short)f2bf(acc[q][ti][tj][j] * (1.0f / S_DEPTH));
                *(sh4*)(smem + nm * 64 + ((w ^ swz) << 3)) = v;
            }
    __syncthreads();

    // ---- stage 2: project P -> C, fused bias, f32 stores ----
    bh8   wpf[8];
    float bpv[8];
    #pragma unroll
    for (int ct = 0; ct < 8; ++ct){
        wpf[ct] = *(const bh8*)(WpT + (ct * 16 + l15) * P_DIM + lq * 8);  // B: col c, k=p
        bpv[ct] = bp[ct * 16 + l15];
    }
    #pragma unroll
    for (int mi = 0; mi < 8; ++mi){
        int mt  = w * 8 + mi;                          // 64 row-tiles / 8 waves
        int nm  = mt * 16 + l15;
        int swz = ((nm >> 1) & 3) ^ (((nm >> 7) & 3) << 1);
        sh4 lo = *(const sh4*)(smem + nm * 64 + (((2 * lq)     ^ swz) << 3));
        sh4 hi = *(const sh4*)(smem + nm * 64 + (((2 * lq + 1) ^ swz) << 3));
        bh8 of = __builtin_shufflevector(lo, hi, 0, 1, 2, 3, 4, 5, 6, 7);  // A: row nm, k=p
        #pragma unroll
        for (int ct = 0; ct < 8; ++ct){
            fx4 d = __builtin_amdgcn_mfma_f32_16x16x32_bf16(
                        of, wpf[ct], fx4{0.f, 0.f, 0.f, 0.f}, 0, 0, 0);
            #pragma unroll
            for (int j = 0; j < 4; ++j){
                int nmr = mt * 16 + lq * 4 + j;        // D row -> nm index
                int n = nmr >> 5, m = nmr & 31;
                out[(((size_t)(n0 + n) * N_RES) + m0 + m) * C_DIM + ct * 16 + l15]
                    = d[j] + bpv[ct];
            }
        }
    }
}

// ---------------------------------------------------------------------------
extern "C" void kernel_launch(void* const* d_in, const int* in_sizes, int n_in,
                              void* d_out, int out_size, void* d_ws, size_t ws_size,
                              hipStream_t stream){
    const float* msa   = (const float*)d_in[0];
    const float* gamma = (const float*)d_in[1];
    const float* beta  = (const float*)d_in[2];
    const float* Wa    = (const float*)d_in[3];
    const float* ba    = (const float*)d_in[4];
    const float* Wb    = (const float*)d_in[5];
    const float* bb    = (const float*)d_in[6];
    const float* Wp    = (const float*)d_in[7];
    const float* bp    = (const float*)d_in[8];
    float* out = (float*)d_out;

    // workspace (ushort elems): aT | bT | W2T(20480) | WpT(4096) | SB(128 f32)
    unsigned short* ws  = (unsigned short*)d_ws;
    unsigned short* aT  = ws;                        // 32*512*128 = 2097152
    unsigned short* bT  = ws + 2097152;
    unsigned short* W2T = ws + 4194304;              // 80*256
    unsigned short* WpT = W2T + 20480;               // 4096
    float*          SB  = (float*)(ws + 4218880);    // 128 f32

    prep_kernel<<<97, 256, 0, stream>>>(Wa, Wb, Wp, gamma, beta, ba, bb, W2T, WpT, SB);
    lnproj_kernel<<<dim3(N_RES, 2), 256, 0, stream>>>(msa, W2T, SB, aT, bT);
    outer_kernel<<<256, 512, 0, stream>>>(aT, bT, WpT, bp, out);
}